// Round 25
// baseline (60.440 us; speedup 1.0000x reference)
//
#include <hip/hip_runtime.h>

#define AS1 __attribute__((address_space(1)))
#define AS3 __attribute__((address_space(3)))
#define CHUNK 256
#define NB 256
#define PIGRID 2048

typedef unsigned int uint;
typedef unsigned short ushort;
typedef __attribute__((ext_vector_type(4))) float f32x4;
typedef __attribute__((ext_vector_type(8))) _Float16 h8;
typedef __attribute__((ext_vector_type(2))) __fp16 fp16x2;

union H8 { uint u[4]; h8 h; };

__device__ __forceinline__ void gld_lds16(const float* g, float* l) {
  __builtin_amdgcn_global_load_lds((const AS1 void*)g, (AS3 void*)l, 16, 0, 0);
}
__device__ __forceinline__ uint pkrtz(float a, float b) {
  union { fp16x2 h; uint u; } c;
  c.h = __builtin_amdgcn_cvt_pkrtz(a, b);
  return c.u;
}

#define WAITVM0  do { asm volatile("s_waitcnt vmcnt(0)" ::: "memory"); __builtin_amdgcn_sched_barrier(0); } while (0)
#define WAITLGKM do { asm volatile("s_waitcnt lgkmcnt(0)" ::: "memory"); __builtin_amdgcn_sched_barrier(0); } while (0)
#define BAR __builtin_amdgcn_s_barrier()

// Fused prep+pi, single round trip (R24: two dependent phases each paid full
// memory latency; occupancy 37->67% changed nothing, so MLP is the lever).
// ALL 8 ri loads are issued FIRST (they don't depend on z — only the wpair
// store does), then the r loads + argmax, sync, then accumulate the landed
// ri values. Invalid tail slots: clamped index + 0/1 mask multiply.
__global__ __launch_bounds__(256) void fused_k(
    const float* __restrict__ r, const float* __restrict__ ri,
    unsigned char* __restrict__ zb, float* __restrict__ wpairf,
    float* __restrict__ pigp, int n)
{
  __shared__ unsigned char zs[256];
  __shared__ float4 s[256];
  const int t = threadIdx.x;
  const int cg = t & 7;
  const int pr = t >> 3;
  const int ppb = (n + PIGRID - 1) / PIGRID;   // 245 for n=500k
  const int p0 = blockIdx.x * ppb;
  const int p1 = min(p0 + ppb, n);
  const float4* rif = (const float4*)ri;

  // ---- issue all 8 ri loads (held in regs; land during argmax) ----
  int px[8]; float msk[8]; float4 rv[8];
#pragma unroll
  for (int j = 0; j < 8; ++j) {
    int p = p0 + pr + j * 32;
    px[j] = p;
    msk[j] = (p < p1) ? 1.f : 0.f;
    int pc = p < p1 ? p : p1 - 1;
    rv[j] = rif[(size_t)pc * 8 + cg];
  }

  // ---- per-thread argmax over r (4 independent loads) ----
  int myp = p0 + t;
  if (t < ppb && myp < n) {
    const float4* rr = (const float4*)(r + (size_t)myp * 16);
    float4 a0 = rr[0], a1 = rr[1], a2 = rr[2], a3 = rr[3];
    float best = a0.x; int z = 0;
#define CHK(v, c) if ((v) > best) { best = (v); z = (c); }
    CHK(a0.y,1) CHK(a0.z,2) CHK(a0.w,3)
    CHK(a1.x,4) CHK(a1.y,5) CHK(a1.z,6) CHK(a1.w,7)
    CHK(a2.x,8) CHK(a2.y,9) CHK(a2.z,10) CHK(a2.w,11)
    CHK(a3.x,12) CHK(a3.y,13) CHK(a3.z,14) CHK(a3.w,15)
#undef CHK
    zs[t] = (unsigned char)z;
    zb[myp] = (unsigned char)z;
  }
  __syncthreads();

  // ---- accumulate + owner wpair store ----
  float4 acc = make_float4(0.f, 0.f, 0.f, 0.f);
#pragma unroll
  for (int j = 0; j < 8; ++j) {
    float4 v = rv[j];
    float m = msk[j];
    if (m != 0.f) {
      int zv = zs[px[j] - p0];
      if (cg == (zv >> 1)) {
        float2 wp = (zv & 1) ? make_float2(v.z, v.w) : make_float2(v.x, v.y);
        *(float2*)&wpairf[(size_t)px[j] * 2] = wp;
      }
    }
    acc.x += v.x * m; acc.y += v.y * m; acc.z += v.z * m; acc.w += v.w * m;
  }
  s[t] = acc;
  __syncthreads();
  if (t < 8) {
    float4 a = s[t];
#pragma unroll
    for (int q = 1; q < 32; ++q) {
      float4 v = s[t + q * 8];
      a.x += v.x; a.y += v.y; a.z += v.z; a.w += v.w;
    }
    *(float4*)&pigp[blockIdx.x * 32 + t * 4] = a;
  }
}

// Gram-MFMA cluster accumulation (R18 proven).
#define CLUSTER_MFMA(CIDX, T00a,T01a,T11a,T20a,T21a, T00b,T01b,T11b,T20b,T21b) { \
  const int c_ = (CIDX); \
  int cnt_ = lcnt[b][c_]; if (cnt_ > 64) cnt_ = 64; \
  const int ng_ = (cnt_ + 31) >> 5; \
  for (int g_ = 0; g_ < ng_; ++g_) { \
    alignas(16) ushort praw_[8]; \
    *(uint4*)praw_ = *(const uint4*)&list[b][c_][(g_ << 5) + ((l >> 4) << 3)]; \
    const int sbase_ = (g_ << 5) + ((l >> 4) << 3); \
    int p_[8]; \
    _Pragma("unroll") for (int j = 0; j < 8; ++j) \
      p_[j] = (sbase_ + j < cnt_) ? (int)praw_[j] : 256; \
    uint W_[8]; \
    _Pragma("unroll") for (int j = 0; j < 8; ++j) W_[j] = wls[b][p_[j]]; \
    H8 F0_, F1_, ws0_, ws1_; \
    _Pragma("unroll") for (int j = 0; j < 4; ++j) { \
      uint l0 = xh[b][p_[2*j]*34 + c16], l1 = xh[b][p_[2*j+1]*34 + c16]; \
      uint h0 = xh[b][p_[2*j]*34 + 16 + c16], h1 = xh[b][p_[2*j+1]*34 + 16 + c16]; \
      F0_.u[j] = l0 | (l1 << 16); \
      F1_.u[j] = h0 | (h1 << 16); \
      ws0_.u[j] = (W_[2*j] & 0xffffu) | (W_[2*j+1] << 16); \
      ws1_.u[j] = (W_[2*j] >> 16) | (W_[2*j+1] & 0xffff0000u); \
    } \
    H8 s00_, s01_, s10_, s11_, i20_, i21_; \
    s00_.h = F0_.h * ws0_.h; s01_.h = F1_.h * ws0_.h; \
    s10_.h = F0_.h * ws1_.h; s11_.h = F1_.h * ws1_.h; \
    _Pragma("unroll") for (int j = 0; j < 4; ++j) { \
      i20_.u[j] = lane16 ? ws0_.u[j] : 0u; \
      i21_.u[j] = lane16 ? ws1_.u[j] : 0u; \
    } \
    T00a = __builtin_amdgcn_mfma_f32_16x16x32_f16(s00_.h, s00_.h, T00a, 0,0,0); \
    T01a = __builtin_amdgcn_mfma_f32_16x16x32_f16(s00_.h, s01_.h, T01a, 0,0,0); \
    T11a = __builtin_amdgcn_mfma_f32_16x16x32_f16(s01_.h, s01_.h, T11a, 0,0,0); \
    T20a = __builtin_amdgcn_mfma_f32_16x16x32_f16(i20_.h, s00_.h, T20a, 0,0,0); \
    T21a = __builtin_amdgcn_mfma_f32_16x16x32_f16(i20_.h, s01_.h, T21a, 0,0,0); \
    T00b = __builtin_amdgcn_mfma_f32_16x16x32_f16(s10_.h, s10_.h, T00b, 0,0,0); \
    T01b = __builtin_amdgcn_mfma_f32_16x16x32_f16(s10_.h, s11_.h, T01b, 0,0,0); \
    T11b = __builtin_amdgcn_mfma_f32_16x16x32_f16(s11_.h, s11_.h, T11b, 0,0,0); \
    T20b = __builtin_amdgcn_mfma_f32_16x16x32_f16(i21_.h, s10_.h, T20b, 0,0,0); \
    T21b = __builtin_amdgcn_mfma_f32_16x16x32_f16(i21_.h, s11_.h, T21b, 0,0,0); \
  } }

// 3KB/comp partials exploiting gram symmetry (verified R19-R24):
// sec0 = Q00 (sym), sec1 = Q11 (sym), sec2 = Q01^T.
#define STORE_MFMA(COMP, T00,T01,T11,T20,T21) { \
  float* dst_ = m2p + ((size_t)blockIdx.x * 32 + (COMP)) * 768; \
  const int r0_ = (l >> 4) << 2; \
  f32x4 t00_ = T00, t01_ = T01, t11_ = T11; \
  *(float4*)&dst_[c16 * 16 + r0_] = *(float4*)&t00_; \
  *(float4*)&dst_[256 + c16 * 16 + r0_] = *(float4*)&t11_; \
  *(float4*)&dst_[512 + c16 * 16 + r0_] = *(float4*)&t01_; \
  if (l < 16) { \
    musp[((size_t)blockIdx.x * 32 + (COMP)) * 32 + l] = T20[0]; \
    musp[((size_t)blockIdx.x * 32 + (COMP)) * 32 + 16 + l] = T21[0]; \
  } }

__global__ __launch_bounds__(512, 2) void mstep_k(
    const float* __restrict__ X, const unsigned char* __restrict__ zb,
    const float* __restrict__ wpairf,
    float* __restrict__ m2p, float* __restrict__ musp, float* __restrict__ dnp,
    int n, int nchunks)
{
  __shared__ float xf32[CHUNK * 32];                 // 32KB gld_lds landing
  __shared__ __align__(16) ushort xh[2][257 * 34];   // fp16 pt-major, row 256 = 0
  __shared__ uint wls[2][257];
  __shared__ __align__(16) ushort list[2][16][64];
  __shared__ int lcnt[2][16];
  __shared__ float dn[16][2];

  const int t = threadIdx.x;
  const int wv = t >> 6;
  const int l = t & 63;
  const int c16 = l & 15;
  const bool lane16 = (l & 15) == 0;
  const int G = gridDim.x;

  f32x4 z4 = {0.f, 0.f, 0.f, 0.f};
  f32x4 a0_00=z4, a0_01=z4, a0_11=z4, a0_20=z4, a0_21=z4;
  f32x4 b0_00=z4, b0_01=z4, b0_11=z4, b0_20=z4, b0_21=z4;
  f32x4 a1_00=z4, a1_01=z4, a1_11=z4, a1_20=z4, a1_21=z4;
  f32x4 b1_00=z4, b1_01=z4, b1_11=z4, b1_20=z4, b1_21=z4;

  float wr0 = 0.f, wr1 = 0.f; int zr = 0;

  auto STAGEX = [&](int ch) {
#pragma unroll
    for (int q = 0; q < 4; ++q) {
      int gi = ch * CHUNK + wv * 32 + q * 8 + (l >> 3);
      if (gi > n - 1) gi = n - 1;
      gld_lds16(X + (size_t)gi * 32 + ((l & 7) << 2), &xf32[(wv * 32 + q * 8) * 32]);
    }
  };
  auto LOADWZ = [&](int ch) {
    if (t < CHUNK) {
      int gi = ch * CHUNK + t;
      if (gi < n) {
        float2 w2 = *(const float2*)(wpairf + (size_t)gi * 2);
        wr0 = w2.x; wr1 = w2.y; zr = zb[gi];
      } else { wr0 = 0.f; wr1 = 0.f; zr = 0; }
    }
  };
  auto CVT = [&](int nb) {
    const int p = t >> 1, hh = t & 1;
    const float4* s4 = (const float4*)(xf32 + p * 32 + hh * 16);
    uint* dst = (uint*)&xh[nb][p * 34 + hh * 16];
#pragma unroll
    for (int i = 0; i < 4; ++i) {
      int ii = (i + p) & 3;
      float4 v = s4[ii];
      dst[2 * ii]     = pkrtz(v.x, v.y);
      dst[2 * ii + 1] = pkrtz(v.z, v.w);
    }
    if (t < CHUNK) {
      wls[nb][t] = pkrtz(sqrtf(wr0), sqrtf(wr1));
      atomicAdd(&dn[zr][0], wr0);
      atomicAdd(&dn[zr][1], wr1);
      int pos = atomicAdd(&lcnt[nb][zr], 1);
      if (pos < 64) list[nb][zr][pos] = (ushort)t;
    }
  };

  if (t < 32) ((int*)lcnt)[t] = 0;
  if (t < 32) ((float*)dn)[t] = 0.f;
  if (t < 17) {
    ((uint*)&xh[0][256 * 34])[t] = 0;
    ((uint*)&xh[1][256 * 34])[t] = 0;
  }
  if (t == 0) { wls[0][256] = 0; wls[1][256] = 0; }

  int ch = blockIdx.x;
  int b = 0;
  if (ch < nchunks) {
    STAGEX(ch); LOADWZ(ch);
    WAITVM0; WAITLGKM; BAR;
    CVT(0);
    WAITLGKM; BAR;
    if (ch + G < nchunks) { STAGEX(ch + G); LOADWZ(ch + G); }
    while (true) {
      CLUSTER_MFMA(wv * 2 + 0, a0_00,a0_01,a0_11,a0_20,a0_21,
                               b0_00,b0_01,b0_11,b0_20,b0_21)
      CLUSTER_MFMA(wv * 2 + 1, a1_00,a1_01,a1_11,a1_20,a1_21,
                               b1_00,b1_01,b1_11,b1_20,b1_21)
      int chn = ch + G;
      if (chn >= nchunks) break;
      WAITVM0; WAITLGKM; BAR;
      if (t < 16) lcnt[b][t] = 0;
      CVT(b ^ 1);
      WAITLGKM; BAR;
      if (chn + G < nchunks) { STAGEX(chn + G); LOADWZ(chn + G); }
      b ^= 1; ch = chn;
    }
  }

  STORE_MFMA((wv * 2 + 0) * 2 + 0, a0_00,a0_01,a0_11,a0_20,a0_21)
  STORE_MFMA((wv * 2 + 0) * 2 + 1, b0_00,b0_01,b0_11,b0_20,b0_21)
  STORE_MFMA((wv * 2 + 1) * 2 + 0, a1_00,a1_01,a1_11,a1_20,a1_21)
  STORE_MFMA((wv * 2 + 1) * 2 + 1, b1_00,b1_01,b1_11,b1_20,b1_21)
  if (t < 32) dnp[blockIdx.x * 32 + t] = dn[t >> 1][t & 1];
}

// Partial-reduction: m2p [NB][24576] via 192 blocks, musp via 8, dnp via 1,
// pigp [PIGRID][32] via 8 slice-blocks (PIGRID/8 rows each -> pigr8[8][32]).
__global__ __launch_bounds__(256) void reduce_k(
    const float* __restrict__ m2p, const float* __restrict__ musp,
    const float* __restrict__ dnp, const float* __restrict__ pigp,
    float* __restrict__ m2r, float* __restrict__ musr,
    float* __restrict__ dnr, float* __restrict__ pigr8, int nb)
{
  const int t = threadIdx.x;
  const int bid = blockIdx.x;

  if (bid < 200) {
    __shared__ float4 red[256];
    const float* in; float* outp; int rs, colbase;
    if (bid < 192) { in = m2p;  outp = m2r;  rs = 24576; colbase = bid * 32; }
    else           { in = musp; outp = musr; rs = 1024;  colbase = (bid - 192) * 32; }
    const int col = colbase + (t & 31);
    float4 a = make_float4(0.f, 0.f, 0.f, 0.f);
#pragma unroll 4
    for (int bb = t >> 5; bb < nb; bb += 8) {
      float4 v = *(const float4*)&in[(size_t)bb * rs + col * 4];
      a.x += v.x; a.y += v.y; a.z += v.z; a.w += v.w;
    }
    red[t] = a;
    __syncthreads();
    if (t < 32) {
      float4 s = red[t];
#pragma unroll
      for (int q = 1; q < 8; ++q) {
        float4 v = red[t + q * 32];
        s.x += v.x; s.y += v.y; s.z += v.z; s.w += v.w;
      }
      *(float4*)&outp[col * 4] = s;
    }
  } else {
    __shared__ float redf[256];
    const float* in; float* outp; int rows, row0;
    if (bid == 200) { in = dnp; outp = dnr; rows = nb; row0 = 0; }
    else {
      in = pigp; outp = pigr8 + (bid - 201) * 32;
      rows = PIGRID / 8; row0 = (bid - 201) * (PIGRID / 8);
    }
    float a = 0.f;
    const int c = t & 31;
#pragma unroll 4
    for (int bb = t >> 5; bb < rows; bb += 8) a += in[(row0 + bb) * 32 + c];
    redf[t] = a;
    __syncthreads();
    if (t < 32) {
      float s = redf[t];
#pragma unroll
      for (int q = 1; q < 8; ++q) s += redf[t + q * 32];
      outp[c] = s;
    }
  }
}

// Epilogue: reconstruct full 32x32 covs from the 3-section symmetric layout.
__global__ __launch_bounds__(256) void finalize_k(
    const float* __restrict__ pigr8, const float* __restrict__ dnr,
    const float* __restrict__ musr, const float* __restrict__ m2r,
    float* __restrict__ out, int n)
{
  const int c = blockIdx.x;
  const int t = threadIdx.x;
  __shared__ float mu[32];
  float safe = fmaxf(dnr[c], 1e-10f);
  if (t < 32) {
    float m = musr[c * 32 + t] / safe;
    mu[t] = m;
    out[32 + c * 32 + t] = m;                        // mus
  }
  if (c == 0 && t < 32) {
    float p = 0.f;
#pragma unroll
    for (int s = 0; s < 8; ++s) p += pigr8[s * 32 + t];
    out[t] = p / (float)n;                           // pi
  }
  __syncthreads();
  const int d1 = t >> 3;
  const int c0 = (t * 4) & 31;
  const float* base = m2r + c * 768;
  float vals[4];
  if (d1 < 16) {
    if (c0 < 16) {
      float4 v = *(const float4*)&base[d1 * 16 + c0];
      vals[0]=v.x; vals[1]=v.y; vals[2]=v.z; vals[3]=v.w;
    } else {
      int cc = c0 - 16;
#pragma unroll
      for (int j = 0; j < 4; ++j) vals[j] = base[512 + (cc + j) * 16 + d1];
    }
  } else {
    int dd = d1 - 16;
    if (c0 < 16) {
      float4 v = *(const float4*)&base[512 + dd * 16 + c0];
      vals[0]=v.x; vals[1]=v.y; vals[2]=v.z; vals[3]=v.w;
    } else {
      float4 v = *(const float4*)&base[256 + dd * 16 + (c0 - 16)];
      vals[0]=v.x; vals[1]=v.y; vals[2]=v.z; vals[3]=v.w;
    }
  }
  float mud1 = mu[d1];
  float4 cov;
  cov.x = vals[0] / safe - mud1 * mu[c0 + 0];
  cov.y = vals[1] / safe - mud1 * mu[c0 + 1];
  cov.z = vals[2] / safe - mud1 * mu[c0 + 2];
  cov.w = vals[3] / safe - mud1 * mu[c0 + 3];
  *(float4*)&out[32 + 1024 + c * 1024 + t * 4] = cov;  // covs
}

extern "C" void kernel_launch(void* const* d_in, const int* in_sizes, int n_in,
                              void* d_out, int out_size, void* d_ws, size_t ws_size,
                              hipStream_t stream) {
  const float* X  = (const float*)d_in[0];
  const float* r  = (const float*)d_in[1];
  const float* ri = (const float*)d_in[2];
  float* out = (float*)d_out;
  const int n = in_sizes[0] / 32;
  const int nchunks = (n + CHUNK - 1) / CHUNK;

  // ws layout: [m2p | musp | dnp | m2r | musr | dnr | pigr8 | pigp | wpair | zbuf]
  float* m2p   = (float*)d_ws;                          // NB*32*768
  float* musp  = m2p + (size_t)NB * 32 * 768;           // NB*32*32
  float* dnp   = musp + (size_t)NB * 32 * 32;           // NB*32
  float* m2r   = dnp + (size_t)NB * 32;                 // 24576
  float* musr  = m2r + 24576;                           // 1024
  float* dnr   = musr + 1024;                           // 32
  float* pigr8 = dnr + 32;                              // 8*32
  float* pigp  = pigr8 + 8 * 32;                        // PIGRID*32
  float* wpair = pigp + (size_t)PIGRID * 32;            // 2n
  unsigned char* zbuf = (unsigned char*)(wpair + 2 * (size_t)n);  // n + pad

  fused_k<<<PIGRID, 256, 0, stream>>>(r, ri, zbuf, wpair, pigp, n);
  mstep_k<<<NB, 512, 0, stream>>>(X, zbuf, wpair, m2p, musp, dnp, n, nchunks);
  reduce_k<<<209, 256, 0, stream>>>(m2p, musp, dnp, pigp, m2r, musr, dnr, pigr8, NB);
  finalize_k<<<32, 256, 0, stream>>>(pigr8, dnr, musr, m2r, out, n);
}

// Round 26
// 53.679 us; speedup vs baseline: 1.1259x; 1.1259x over previous
//
#include <hip/hip_runtime.h>

#define AS1 __attribute__((address_space(1)))
#define AS3 __attribute__((address_space(3)))
#define CHUNK 256
#define NB 256

typedef unsigned int uint;
typedef unsigned short ushort;
typedef __attribute__((ext_vector_type(4))) float f32x4;
typedef __attribute__((ext_vector_type(8))) _Float16 h8;
typedef __attribute__((ext_vector_type(2))) __fp16 fp16x2;

union H8 { uint u[4]; h8 h; };

__device__ __forceinline__ void gld_lds16(const float* g, float* l) {
  __builtin_amdgcn_global_load_lds((const AS1 void*)g, (AS3 void*)l, 16, 0, 0);
}
__device__ __forceinline__ uint pkrtz(float a, float b) {
  union { fp16x2 h; uint u; } c;
  c.h = __builtin_amdgcn_cvt_pkrtz(a, b);
  return c.u;
}

#define WAITVM0  do { asm volatile("s_waitcnt vmcnt(0)" ::: "memory"); __builtin_amdgcn_sched_barrier(0); } while (0)
#define WAITLGKM do { asm volatile("s_waitcnt lgkmcnt(0)" ::: "memory"); __builtin_amdgcn_sched_barrier(0); } while (0)
#define BAR __builtin_amdgcn_s_barrier()

// Gram-MFMA cluster accumulation (R18-R25 proven; xh now single-buffered).
#define CLUSTER_MFMA(CIDX, B, T00a,T01a,T11a,T20a,T21a, T00b,T01b,T11b,T20b,T21b) { \
  const int c_ = (CIDX); \
  int cnt_ = lcnt[B][c_]; if (cnt_ > 64) cnt_ = 64; \
  const int ng_ = (cnt_ + 31) >> 5; \
  for (int g_ = 0; g_ < ng_; ++g_) { \
    alignas(16) ushort praw_[8]; \
    *(uint4*)praw_ = *(const uint4*)&list[B][c_][(g_ << 5) + ((l >> 4) << 3)]; \
    const int sbase_ = (g_ << 5) + ((l >> 4) << 3); \
    int p_[8]; \
    _Pragma("unroll") for (int j = 0; j < 8; ++j) \
      p_[j] = (sbase_ + j < cnt_) ? (int)praw_[j] : 256; \
    uint W_[8]; \
    _Pragma("unroll") for (int j = 0; j < 8; ++j) W_[j] = wls[B][p_[j]]; \
    H8 F0_, F1_, ws0_, ws1_; \
    _Pragma("unroll") for (int j = 0; j < 4; ++j) { \
      uint l0 = xh[p_[2*j]*34 + c16], l1 = xh[p_[2*j+1]*34 + c16]; \
      uint h0 = xh[p_[2*j]*34 + 16 + c16], h1 = xh[p_[2*j+1]*34 + 16 + c16]; \
      F0_.u[j] = l0 | (l1 << 16); \
      F1_.u[j] = h0 | (h1 << 16); \
      ws0_.u[j] = (W_[2*j] & 0xffffu) | (W_[2*j+1] << 16); \
      ws1_.u[j] = (W_[2*j] >> 16) | (W_[2*j+1] & 0xffff0000u); \
    } \
    H8 s00_, s01_, s10_, s11_, i20_, i21_; \
    s00_.h = F0_.h * ws0_.h; s01_.h = F1_.h * ws0_.h; \
    s10_.h = F0_.h * ws1_.h; s11_.h = F1_.h * ws1_.h; \
    _Pragma("unroll") for (int j = 0; j < 4; ++j) { \
      i20_.u[j] = lane16 ? ws0_.u[j] : 0u; \
      i21_.u[j] = lane16 ? ws1_.u[j] : 0u; \
    } \
    T00a = __builtin_amdgcn_mfma_f32_16x16x32_f16(s00_.h, s00_.h, T00a, 0,0,0); \
    T01a = __builtin_amdgcn_mfma_f32_16x16x32_f16(s00_.h, s01_.h, T01a, 0,0,0); \
    T11a = __builtin_amdgcn_mfma_f32_16x16x32_f16(s01_.h, s01_.h, T11a, 0,0,0); \
    T20a = __builtin_amdgcn_mfma_f32_16x16x32_f16(i20_.h, s00_.h, T20a, 0,0,0); \
    T21a = __builtin_amdgcn_mfma_f32_16x16x32_f16(i20_.h, s01_.h, T21a, 0,0,0); \
    T00b = __builtin_amdgcn_mfma_f32_16x16x32_f16(s10_.h, s10_.h, T00b, 0,0,0); \
    T01b = __builtin_amdgcn_mfma_f32_16x16x32_f16(s10_.h, s11_.h, T01b, 0,0,0); \
    T11b = __builtin_amdgcn_mfma_f32_16x16x32_f16(s11_.h, s11_.h, T11b, 0,0,0); \
    T20b = __builtin_amdgcn_mfma_f32_16x16x32_f16(i21_.h, s10_.h, T20b, 0,0,0); \
    T21b = __builtin_amdgcn_mfma_f32_16x16x32_f16(i21_.h, s11_.h, T21b, 0,0,0); \
  } }

// 3KB/comp partials exploiting gram symmetry (verified R19-R25).
#define STORE_MFMA(COMP, T00,T01,T11,T20,T21) { \
  float* dst_ = m2p + ((size_t)blockIdx.x * 32 + (COMP)) * 768; \
  const int r0_ = (l >> 4) << 2; \
  f32x4 t00_ = T00, t01_ = T01, t11_ = T11; \
  *(float4*)&dst_[c16 * 16 + r0_] = *(float4*)&t00_; \
  *(float4*)&dst_[256 + c16 * 16 + r0_] = *(float4*)&t11_; \
  *(float4*)&dst_[512 + c16 * 16 + r0_] = *(float4*)&t01_; \
  if (l < 16) { \
    musp[((size_t)blockIdx.x * 32 + (COMP)) * 32 + l] = T20[0]; \
    musp[((size_t)blockIdx.x * 32 + (COMP)) * 32 + 16 + l] = T21[0]; \
  } }

// Single-pass mega-kernel: each block owns its chunks end-to-end.
// Per 256-pt chunk: stage X + ri via gld_lds, r -> regs (t<256); PREP does
// argmax (regs) -> w pair from ril LDS row -> wls/list/dn + CVT + pi acc.
// No zb/wpair intermediates, no separate fused pass (R25: two serialized
// latency-padded streaming kernels were the remaining structural cost).
__global__ __launch_bounds__(512, 1) void giant_k(
    const float* __restrict__ X, const float* __restrict__ r,
    const float* __restrict__ ri,
    float* __restrict__ m2p, float* __restrict__ musp, float* __restrict__ dnp,
    float* __restrict__ pigp, int n, int nchunks)
{
  __shared__ float xf32[CHUNK * 32];                 // 32KB X landing
  __shared__ float ril[CHUNK * 32];                  // 32KB ri landing
  __shared__ __align__(16) ushort xh[257 * 34];      // 17.5KB fp16, row 256 = 0
  __shared__ uint wls[2][257];
  __shared__ __align__(16) ushort list[2][16][64];
  __shared__ int lcnt[2][16];
  __shared__ float dn[16][2];

  const int t = threadIdx.x;
  const int wv = t >> 6;
  const int l = t & 63;
  const int c16 = l & 15;
  const bool lane16 = (l & 15) == 0;
  const int G = gridDim.x;

  f32x4 z4 = {0.f, 0.f, 0.f, 0.f};
  f32x4 a0_00=z4, a0_01=z4, a0_11=z4, a0_20=z4, a0_21=z4;
  f32x4 b0_00=z4, b0_01=z4, b0_11=z4, b0_20=z4, b0_21=z4;
  f32x4 a1_00=z4, a1_01=z4, a1_11=z4, a1_20=z4, a1_21=z4;
  f32x4 b1_00=z4, b1_01=z4, b1_11=z4, b1_20=z4, b1_21=z4;
  float4 ppi = make_float4(0.f, 0.f, 0.f, 0.f);      // pi partial (cols (t&7)*4..+3)
  float4 rA = ppi, rB = ppi, rC = ppi, rD = ppi;     // r row regs (t<256)

  auto STAGEX = [&](int ch) {
#pragma unroll
    for (int q = 0; q < 4; ++q) {
      int gi = ch * CHUNK + wv * 32 + q * 8 + (l >> 3);
      if (gi > n - 1) gi = n - 1;
      gld_lds16(X + (size_t)gi * 32 + ((l & 7) << 2), &xf32[(wv * 32 + q * 8) * 32]);
    }
  };
  auto STAGERI = [&](int ch) {
#pragma unroll
    for (int q = 0; q < 4; ++q) {
      int gi = ch * CHUNK + wv * 32 + q * 8 + (l >> 3);
      if (gi > n - 1) gi = n - 1;
      gld_lds16(ri + (size_t)gi * 32 + ((l & 7) << 2), &ril[(wv * 32 + q * 8) * 32]);
    }
  };
  auto LOADR = [&](int ch) {
    if (t < CHUNK) {
      int gi = ch * CHUNK + t;
      if (gi > n - 1) gi = n - 1;
      const float4* rr = (const float4*)(r + (size_t)gi * 16);
      rA = rr[0]; rB = rr[1]; rC = rr[2]; rD = rr[3];
    }
  };
  auto PREP = [&](int ch, int b) {
    int rem = n - ch * CHUNK; if (rem > CHUNK) rem = CHUNK;
    // CVT xf32 -> xh (all threads; proven rotated pattern)
    {
      const int p = t >> 1, hh = t & 1;
      const float4* s4c = (const float4*)(xf32 + p * 32 + hh * 16);
      uint* dst = (uint*)&xh[p * 34 + hh * 16];
#pragma unroll
      for (int i = 0; i < 4; ++i) {
        int ii = (i + p) & 3;
        float4 v = s4c[ii];
        dst[2 * ii]     = pkrtz(v.x, v.y);
        dst[2 * ii + 1] = pkrtz(v.z, v.w);
      }
    }
    // argmax (regs) + w from ril row + wls/list/dn (t<rem)
    if (t < rem) {
      float best = rA.x; int z = 0;
#define CHK(v, c) if ((v) > best) { best = (v); z = (c); }
      CHK(rA.y,1) CHK(rA.z,2) CHK(rA.w,3)
      CHK(rB.x,4) CHK(rB.y,5) CHK(rB.z,6) CHK(rB.w,7)
      CHK(rC.x,8) CHK(rC.y,9) CHK(rC.z,10) CHK(rC.w,11)
      CHK(rD.x,12) CHK(rD.y,13) CHK(rD.z,14) CHK(rD.w,15)
#undef CHK
      float2 w2 = *(const float2*)&ril[t * 32 + 2 * z];
      wls[b][t] = pkrtz(sqrtf(w2.x), sqrtf(w2.y));
      atomicAdd(&dn[z][0], w2.x);
      atomicAdd(&dn[z][1], w2.y);
      int pos = atomicAdd(&lcnt[b][z], 1);
      if (pos < 64) list[b][z][pos] = (ushort)t;
    }
    if (t < 16) lcnt[b ^ 1][t] = 0;
    // pi accumulate from ril (all threads; float4 index t + k*512)
    const float4* r4 = (const float4*)ril;
#pragma unroll
    for (int k = 0; k < 4; ++k) {
      int fi = t + k * 512;
      if ((fi >> 3) < rem) {
        float4 v = r4[fi];
        ppi.x += v.x; ppi.y += v.y; ppi.z += v.z; ppi.w += v.w;
      }
    }
  };

  if (t < 32) { ((int*)lcnt)[t] = 0; ((float*)dn)[t] = 0.f; }
  if (t < 17) ((uint*)&xh[256 * 34])[t] = 0;
  if (t == 0) { wls[0][256] = 0; wls[1][256] = 0; }

  int ch = blockIdx.x;
  int b = 0;
  if (ch < nchunks) {
    STAGEX(ch); STAGERI(ch); LOADR(ch);
    WAITVM0; WAITLGKM; BAR;            // landing(ch) + zeros visible
    while (true) {
      PREP(ch, b);
      WAITLGKM; BAR;                   // xh/wls[b]/list[b] ready; landing free
      int chn = ch + G;
      if (chn < nchunks) { STAGEX(chn); STAGERI(chn); LOADR(chn); }
      CLUSTER_MFMA(wv * 2 + 0, b, a0_00,a0_01,a0_11,a0_20,a0_21,
                                  b0_00,b0_01,b0_11,b0_20,b0_21)
      CLUSTER_MFMA(wv * 2 + 1, b, a1_00,a1_01,a1_11,a1_20,a1_21,
                                  b1_00,b1_01,b1_11,b1_20,b1_21)
      if (chn >= nchunks) break;
      BAR;                             // xh/wls/list reads done
      WAITVM0;                         // landing(chn) + r regs landed
      b ^= 1; ch = chn;
    }
  }

  STORE_MFMA((wv * 2 + 0) * 2 + 0, a0_00,a0_01,a0_11,a0_20,a0_21)
  STORE_MFMA((wv * 2 + 0) * 2 + 1, b0_00,b0_01,b0_11,b0_20,b0_21)
  STORE_MFMA((wv * 2 + 1) * 2 + 0, a1_00,a1_01,a1_11,a1_20,a1_21)
  STORE_MFMA((wv * 2 + 1) * 2 + 1, b1_00,b1_01,b1_11,b1_20,b1_21)
  if (t < 32) dnp[blockIdx.x * 32 + t] = dn[t >> 1][t & 1];

  // pi block-reduce (reuse ril as scratch; all MFMA/PREP reads of ril done)
  __syncthreads();
  float4* s4 = (float4*)ril;
  s4[t] = ppi;
  __syncthreads();
  if (t < 8) {
    float4 a = s4[t];
#pragma unroll
    for (int q = 1; q < 64; ++q) {
      float4 v = s4[t + q * 8];
      a.x += v.x; a.y += v.y; a.z += v.z; a.w += v.w;
    }
    *(float4*)&pigp[blockIdx.x * 32 + t * 4] = a;
  }
}

// Partial-reduction: m2p [NB][24576] via 192 blocks, musp via 8, dnp via 1,
// pigp [NB][32] via 8 slice-blocks (NB/8 rows each -> pigr8[8][32]).
__global__ __launch_bounds__(256) void reduce_k(
    const float* __restrict__ m2p, const float* __restrict__ musp,
    const float* __restrict__ dnp, const float* __restrict__ pigp,
    float* __restrict__ m2r, float* __restrict__ musr,
    float* __restrict__ dnr, float* __restrict__ pigr8, int nb)
{
  const int t = threadIdx.x;
  const int bid = blockIdx.x;

  if (bid < 200) {
    __shared__ float4 red[256];
    const float* in; float* outp; int rs, colbase;
    if (bid < 192) { in = m2p;  outp = m2r;  rs = 24576; colbase = bid * 32; }
    else           { in = musp; outp = musr; rs = 1024;  colbase = (bid - 192) * 32; }
    const int col = colbase + (t & 31);
    float4 a = make_float4(0.f, 0.f, 0.f, 0.f);
#pragma unroll 4
    for (int bb = t >> 5; bb < nb; bb += 8) {
      float4 v = *(const float4*)&in[(size_t)bb * rs + col * 4];
      a.x += v.x; a.y += v.y; a.z += v.z; a.w += v.w;
    }
    red[t] = a;
    __syncthreads();
    if (t < 32) {
      float4 s = red[t];
#pragma unroll
      for (int q = 1; q < 8; ++q) {
        float4 v = red[t + q * 32];
        s.x += v.x; s.y += v.y; s.z += v.z; s.w += v.w;
      }
      *(float4*)&outp[col * 4] = s;
    }
  } else {
    __shared__ float redf[256];
    const float* in; float* outp; int rows, row0;
    if (bid == 200) { in = dnp; outp = dnr; rows = nb; row0 = 0; }
    else {
      in = pigp; outp = pigr8 + (bid - 201) * 32;
      rows = nb / 8; row0 = (bid - 201) * (nb / 8);
    }
    float a = 0.f;
    const int c = t & 31;
#pragma unroll 4
    for (int bb = t >> 5; bb < rows; bb += 8) a += in[(row0 + bb) * 32 + c];
    redf[t] = a;
    __syncthreads();
    if (t < 32) {
      float s = redf[t];
#pragma unroll
      for (int q = 1; q < 8; ++q) s += redf[t + q * 32];
      outp[c] = s;
    }
  }
}

// Epilogue: reconstruct full 32x32 covs from the 3-section symmetric layout.
__global__ __launch_bounds__(256) void finalize_k(
    const float* __restrict__ pigr8, const float* __restrict__ dnr,
    const float* __restrict__ musr, const float* __restrict__ m2r,
    float* __restrict__ out, int n)
{
  const int c = blockIdx.x;
  const int t = threadIdx.x;
  __shared__ float mu[32];
  float safe = fmaxf(dnr[c], 1e-10f);
  if (t < 32) {
    float m = musr[c * 32 + t] / safe;
    mu[t] = m;
    out[32 + c * 32 + t] = m;                        // mus
  }
  if (c == 0 && t < 32) {
    float p = 0.f;
#pragma unroll
    for (int s = 0; s < 8; ++s) p += pigr8[s * 32 + t];
    out[t] = p / (float)n;                           // pi
  }
  __syncthreads();
  const int d1 = t >> 3;
  const int c0 = (t * 4) & 31;
  const float* base = m2r + c * 768;
  float vals[4];
  if (d1 < 16) {
    if (c0 < 16) {
      float4 v = *(const float4*)&base[d1 * 16 + c0];
      vals[0]=v.x; vals[1]=v.y; vals[2]=v.z; vals[3]=v.w;
    } else {
      int cc = c0 - 16;
#pragma unroll
      for (int j = 0; j < 4; ++j) vals[j] = base[512 + (cc + j) * 16 + d1];
    }
  } else {
    int dd = d1 - 16;
    if (c0 < 16) {
      float4 v = *(const float4*)&base[512 + dd * 16 + c0];
      vals[0]=v.x; vals[1]=v.y; vals[2]=v.z; vals[3]=v.w;
    } else {
      float4 v = *(const float4*)&base[256 + dd * 16 + (c0 - 16)];
      vals[0]=v.x; vals[1]=v.y; vals[2]=v.z; vals[3]=v.w;
    }
  }
  float mud1 = mu[d1];
  float4 cov;
  cov.x = vals[0] / safe - mud1 * mu[c0 + 0];
  cov.y = vals[1] / safe - mud1 * mu[c0 + 1];
  cov.z = vals[2] / safe - mud1 * mu[c0 + 2];
  cov.w = vals[3] / safe - mud1 * mu[c0 + 3];
  *(float4*)&out[32 + 1024 + c * 1024 + t * 4] = cov;  // covs
}

extern "C" void kernel_launch(void* const* d_in, const int* in_sizes, int n_in,
                              void* d_out, int out_size, void* d_ws, size_t ws_size,
                              hipStream_t stream) {
  const float* X  = (const float*)d_in[0];
  const float* r  = (const float*)d_in[1];
  const float* ri = (const float*)d_in[2];
  float* out = (float*)d_out;
  const int n = in_sizes[0] / 32;
  const int nchunks = (n + CHUNK - 1) / CHUNK;

  // ws layout: [m2p | musp | dnp | m2r | musr | dnr | pigr8 | pigp]
  float* m2p   = (float*)d_ws;                          // NB*32*768
  float* musp  = m2p + (size_t)NB * 32 * 768;           // NB*32*32
  float* dnp   = musp + (size_t)NB * 32 * 32;           // NB*32
  float* m2r   = dnp + (size_t)NB * 32;                 // 24576
  float* musr  = m2r + 24576;                           // 1024
  float* dnr   = musr + 1024;                           // 32
  float* pigr8 = dnr + 32;                              // 8*32
  float* pigp  = pigr8 + 8 * 32;                        // NB*32

  giant_k<<<NB, 512, 0, stream>>>(X, r, ri, m2p, musp, dnp, pigp, n, nchunks);
  reduce_k<<<209, 256, 0, stream>>>(m2p, musp, dnp, pigp, m2r, musr, dnr, pigr8, NB);
  finalize_k<<<32, 256, 0, stream>>>(pigr8, dnr, musr, m2r, out, n);
}